// Round 13
// baseline (278.581 us; speedup 1.0000x reference)
//
#include <hip/hip_runtime.h>
#include <hip/hip_fp16.h>

#define GN 256
#define NPG 360
#define NN (GN*NPG)      // 92160
#define DEGAVG 16
#define EE (NN*DEGAVG)   // 1474560
#define EPG (NPG*DEGAVG) // 5760 edges per graph
#define HH 5
#define CC 30
#define IN_CH 11
#define NUM_GC 9
#define EPS 1e-5f

#define HLS 36   // h_l/agg_l row stride (floats): 144B, 16B-aligned -> b128 rows
#define SSS 5    // ssrc/sdst row stride
#define XS 12    // x row stride (floats): 16B-aligned rows

// ---- LDS layout (bytes) ----
#define OFF_HL     0        // f32 [360*36] = 51840
#define OFF_AGG    51840    // f32 [360*36] = 51840 ; EGAT aliases {x 17280|ssrc 7200|sdst 7200}
#define OFF_EDGE   103680   // u32 [5760]   = 23040
#define OFF_ROWP   126720   // u16 [364]    = 728
#define OFF_DEG    127448   // u32 [360]    = 1440
#define OFF_POOL   128888   // f32 [300]    = 1200
#define OFF_FCH    130088   // f32 [56]     = 224
#define OFF_WA     130312   // f32 [112]    = 448
#define OFF_WSUM   130760   // u32 [18]     = 72
#define SMEM_TOTAL 130832

__device__ __forceinline__ float f16_to_f32(unsigned short us) {
  __half_raw r; r.x = us; return __half2float(r);
}
__device__ __forceinline__ unsigned short f32_to_f16(float f) {
  __half h = __float2half(f);
  __half_raw r = *reinterpret_cast<__half_raw*>(&h);
  return r.x;
}

// ---------- InstanceNorm (in place, f32) + per-graph max pool: 30 ch x 32 lanes ----------
__device__ __forceinline__ void norm_pool(float* h_l, float* pooled_l, int layer, int tid) {
  int c = tid >> 5, jj = tid & 31;
  if (c < CC) {
    float va[12];
    float s = 0.f, s2 = 0.f;
#pragma unroll
    for (int t = 0; t < 12; t++) {
      int i = jj + t * 32;
      float v = (i < NPG) ? h_l[i * HLS + c] : 0.f;
      va[t] = v; s += v; s2 += v * v;
    }
#pragma unroll
    for (int m = 16; m >= 1; m >>= 1) { s += __shfl_xor(s, m); s2 += __shfl_xor(s2, m); }
    float mean = s * (1.f / NPG);
    float rs = rsqrtf(s2 * (1.f / NPG) - mean * mean + EPS);
    float mx = -1e30f;
#pragma unroll
    for (int t = 0; t < 12; t++) {
      int i = jj + t * 32;
      if (i < NPG) {
        float v = (va[t] - mean) * rs;
        h_l[i * HLS + c] = v;
        mx = fmaxf(mx, v);
      }
    }
#pragma unroll
    for (int m = 16; m >= 1; m >>= 1) mx = fmaxf(mx, __shfl_xor(mx, m));
    if (jj == 0) pooled_l[layer * CC + c] = mx;
  }
}

// ---------- GraphConv matmul half: b128 row loads, compile-time weight indices ----------
template <int CB>
__device__ __forceinline__ void mm_half(int n, const float* h_l, const float* agg_l,
                                        const float* Wr, const float* Wn, const float* bs,
                                        float* acc) {
#pragma unroll
  for (int c = 0; c < 15; c++) acc[c] = bs[CB + c];
  float hv[32];
  const float4* hr4 = (const float4*)(h_l + n * HLS);
#pragma unroll
  for (int t = 0; t < 8; t++) {
    float4 v = hr4[t];
    hv[4 * t] = v.x; hv[4 * t + 1] = v.y; hv[4 * t + 2] = v.z; hv[4 * t + 3] = v.w;
  }
#pragma unroll
  for (int k = 0; k < CC; k++) {
    float hk = hv[k];
#pragma unroll
    for (int c = 0; c < 15; c++) acc[c] = fmaf(hk, Wr[k * CC + CB + c], acc[c]);
  }
  const float4* ar4 = (const float4*)(agg_l + n * HLS);
#pragma unroll
  for (int t = 0; t < 8; t++) {
    float4 v = ar4[t];
    hv[4 * t] = v.x; hv[4 * t + 1] = v.y; hv[4 * t + 2] = v.z; hv[4 * t + 3] = v.w;
  }
#pragma unroll
  for (int k = 0; k < CC; k++) {
    float ak = hv[k];
#pragma unroll
    for (int c = 0; c < 15; c++) acc[c] = fmaf(ak, Wn[k * CC + CB + c], acc[c]);
  }
}

// ---------- mega-kernel ----------
__global__ __launch_bounds__(1024, 4) void k_mega(
    const float* __restrict__ x, const int* __restrict__ ei, const float* __restrict__ eattr,
    const float* __restrict__ egw, const float* __restrict__ att_s,
    const float* __restrict__ att_d, const float* __restrict__ att_e,
    const float* __restrict__ wroot, const float* __restrict__ wnbr,
    const float* __restrict__ gcb,
    const float* __restrict__ fc1w, const float* __restrict__ fc1b,
    const float* __restrict__ fc2w, const float* __restrict__ fc2b,
    float* __restrict__ out) {
  __shared__ __align__(16) unsigned char smem[SMEM_TOTAL];
  float*          h_l     = (float*)(smem + OFF_HL);
  float*          agg_l   = (float*)(smem + OFF_AGG);
  unsigned*       edge_l  = (unsigned*)(smem + OFF_EDGE);
  float*          x_l     = (float*)(smem + OFF_AGG);               // EGAT-phase aliases
  float*          ssrc_l  = (float*)(smem + OFF_AGG) + NPG * XS;
  float*          sdst_l  = (float*)(smem + OFF_AGG) + NPG * XS + NPG * SSS;
  unsigned short* rowp_l  = (unsigned short*)(smem + OFF_ROWP);
  unsigned*       deg_l   = (unsigned*)(smem + OFF_DEG);
  float*          pooled_l= (float*)(smem + OFF_POOL);
  float*          fch     = (float*)(smem + OFF_FCH);
  float*          wa_l    = (float*)(smem + OFF_WA);
  unsigned*       wsum    = (unsigned*)(smem + OFF_WSUM);

  const int g = blockIdx.x, tid = threadIdx.x;
  const int nb = g * NPG;
  const int ebase = g * EPG;            // edges are graph-contiguous by construction
  const int lane = tid & 63, wid = tid >> 6;

  // ---- P0: zero deg + h pad cols (30,31 stay zero forever), stage x ----
  for (int i = tid; i < NPG; i += 1024) deg_l[i] = 0u;
  for (int i = tid; i < NPG * 2; i += 1024) h_l[(i >> 1) * HLS + 30 + (i & 1)] = 0.f;
  for (int it = tid; it < NPG * XS; it += 1024) {
    int n = it / XS, i = it - n * XS;
    x_l[it] = (i < IN_CH) ? x[(size_t)(nb + n) * IN_CH + i] : 0.f;
  }
  __syncthreads();

  // ---- P1: degree histogram (LDS atomics) + wa precontraction ----
  for (int e = tid; e < EPG; e += 1024) {
    int d = ei[EE + ebase + e] - nb;
    atomicAdd(&deg_l[d], 1u);
  }
  if (tid < 110) {
    int half = tid >= 55;
    int idx = tid - half * 55;
    int i = idx / 5, h = idx - i * 5;
    const float* av = half ? att_d : att_s;
    float s = 0.f;
#pragma unroll
    for (int c = 0; c < CC; c++) s += egw[(i * HH + h) * CC + c] * av[h * CC + c];
    wa_l[tid] = s;
  }
  __syncthreads();

  // ---- P2: block scan of degrees -> rowp_l ----
  {
    unsigned v = (tid < NPG) ? deg_l[tid] : 0u;
#pragma unroll
    for (int off = 1; off < 64; off <<= 1) {
      unsigned t = (unsigned)__shfl_up((int)v, off);
      if (lane >= off) v += t;
    }
    if (lane == 63) wsum[wid] = v;
    __syncthreads();
    if (tid == 0) {
      unsigned run = 0;
      for (int i = 0; i < 16; i++) { unsigned t = wsum[i]; wsum[i] = run; run += t; }
    }
    __syncthreads();
    if (tid < NPG) rowp_l[tid + 1] = (unsigned short)(v + wsum[wid]);
    if (tid == 0) rowp_l[0] = 0;
    if (tid < NPG) deg_l[tid] = 0u;     // becomes scatter cursor
  }
  __syncthreads();

  // ---- P3: scatter edges into CSR (raw src | eattr_f16) + ssrc/sdst dots ----
  for (int e = tid; e < EPG; e += 1024) {
    int s = ei[ebase + e] - nb;
    int d = ei[EE + ebase + e] - nb;
    float ea = eattr[ebase + e];
    unsigned pos = (unsigned)rowp_l[d] + atomicAdd(&deg_l[d], 1u);
    edge_l[pos] = (unsigned)s | ((unsigned)f32_to_f16(ea) << 16);
  }
  if (tid < NPG) {
    float xi[IN_CH];
#pragma unroll
    for (int i = 0; i < IN_CH; i++) xi[i] = x_l[tid * XS + i];
#pragma unroll
    for (int h = 0; h < HH; h++) {
      float s1 = 0.f, s2 = 0.f;
#pragma unroll
      for (int i = 0; i < IN_CH; i++) {
        s1 = fmaf(xi[i], wa_l[i * HH + h], s1);
        s2 = fmaf(xi[i], wa_l[55 + i * HH + h], s2);
      }
      ssrc_l[tid * SSS + h] = s1;
      sdst_l[tid * SSS + h] = s2;
    }
  }
  __syncthreads();

  // ---- P4: EGAT thread-per-node, 2 passes (max-shift cancels; |logit| small) ----
  if (tid < NPG) {
    const int n = tid;
    const int b = rowp_l[n], en = rowp_l[n + 1];
    float sd[HH], ae[HH];
#pragma unroll
    for (int h = 0; h < HH; h++) { sd[h] = sdst_l[n * SSS + h]; ae[h] = att_e[h]; }
    float dn[HH];
#pragma unroll
    for (int h = 0; h < HH; h++) dn[h] = 0.f;
    for (int p = b; p < en; p++) {            // pass 1: denominators
      unsigned u = edge_l[p];
      int s = u & 0xffffu;
      float ea = f16_to_f32((unsigned short)(u >> 16));
      const float* sr = ssrc_l + s * SSS;
#pragma unroll
      for (int h = 0; h < HH; h++) {
        float lg = sr[h] + sd[h] + ea * ae[h];
        lg = lg > 0.f ? lg : 0.2f * lg;
        dn[h] += __expf(lg);
      }
    }
    float rdn[HH];
#pragma unroll
    for (int h = 0; h < HH; h++) rdn[h] = 1.f / (dn[h] + 1e-16f);
    float gg[55];
#pragma unroll
    for (int k = 0; k < 55; k++) gg[k] = 0.f;
    for (int p = b; p < en; p++) {            // pass 2: alpha, 11-dim gather, edge rewrite
      unsigned u = edge_l[p];
      int s = u & 0xffffu;
      float ea = f16_to_f32((unsigned short)(u >> 16));
      const float* sr = ssrc_l + s * SSS;
      const float* xr = x_l + s * XS;
      const float4 xv0 = *(const float4*)(xr);
      const float4 xv1 = *(const float4*)(xr + 4);
      const float4 xv2 = *(const float4*)(xr + 8);
      const float xi[IN_CH] = {xv0.x, xv0.y, xv0.z, xv0.w, xv1.x, xv1.y, xv1.z, xv1.w,
                               xv2.x, xv2.y, xv2.z};
      float ews = 0.f;
#pragma unroll
      for (int h = 0; h < HH; h++) {
        float lg = sr[h] + sd[h] + ea * ae[h];
        lg = lg > 0.f ? lg : 0.2f * lg;
        float a = __expf(lg) * rdn[h];
        ews += a;
#pragma unroll
        for (int i = 0; i < IN_CH; i++) gg[h * IN_CH + i] = fmaf(a, xi[i], gg[h * IN_CH + i]);
      }
      // rewrite edge: premultiplied h_l float offset | f16(mean-head alpha)
      edge_l[p] = (unsigned)(s * HLS) | ((unsigned)f32_to_f16(ews * 0.2f) << 16);
    }
    // h = 0.2 * sum_h g_h . W_h  (uniform scalar weight loads)
#pragma unroll
    for (int half = 0; half < 2; half++) {
      float acc[15];
#pragma unroll
      for (int c = 0; c < 15; c++) acc[c] = 0.f;
#pragma unroll
      for (int i = 0; i < IN_CH; i++) {
#pragma unroll
        for (int h = 0; h < HH; h++) {
          float gv = gg[h * IN_CH + i];
          const float* wr = egw + (i * HH + h) * CC + half * 15;
#pragma unroll
          for (int c = 0; c < 15; c++) acc[c] = fmaf(gv, wr[c], acc[c]);
        }
      }
#pragma unroll
      for (int c = 0; c < 15; c++) h_l[n * HLS + half * 15 + c] = 0.2f * acc[c];
    }
  }
  __syncthreads();

  // ---- P5: norm0 + pooled[0] ----
  norm_pool(h_l, pooled_l, 0, tid);
  __syncthreads();

  // ---- GC stack ----
  const int es = lane >> 3;          // edge slot 0..7
  const int q  = lane & 7;           // channel quad: ch 4q..4q+3 (q=7 reads pad zeros)
#pragma unroll 1
  for (int l = 0; l < NUM_GC; l++) {
    // gather: wave per node, 8 edges x 8 quad-lanes x ds_read_b128 (1 KB per instr).
    // bank-quad (9s+q)%8; edge words broadcast across q-groups.
    for (int n = wid; n < NPG; n += 16) {
      int b = rowp_l[n], en = rowp_l[n + 1];
      float a0 = 0.f, a1 = 0.f, a2 = 0.f, a3 = 0.f;
      for (int p = b + es; p < en; p += 8) {
        unsigned u = edge_l[p];
        float w = f16_to_f32((unsigned short)(u >> 16));
        const float4 v = *(const float4*)(h_l + (u & 0xffffu) + 4 * q);
        a0 = fmaf(w, v.x, a0); a1 = fmaf(w, v.y, a1);
        a2 = fmaf(w, v.z, a2); a3 = fmaf(w, v.w, a3);
      }
#pragma unroll
      for (int m = 8; m <= 32; m <<= 1) {
        a0 += __shfl_xor(a0, m); a1 += __shfl_xor(a1, m);
        a2 += __shfl_xor(a2, m); a3 += __shfl_xor(a3, m);
      }
      if (es == 0)
        *(float4*)(agg_l + n * HLS + 4 * q) = make_float4(a0, a1, a2, a3);
    }
    __syncthreads();
    // matmul halves: compute (reads) -> barrier -> write (avoids cross-half RW race)
    const float* Wr = wroot + l * CC * CC;
    const float* Wn = wnbr + l * CC * CC;
    const float* bs = gcb + l * CC;
    float acc[15];
    int n = -1, cb = 0;
    if (tid < NPG) { n = tid; cb = 0; mm_half<0>(n, h_l, agg_l, Wr, Wn, bs, acc); }
    else if (tid >= 512 && tid < 512 + NPG) { n = tid - 512; cb = 15; mm_half<15>(n, h_l, agg_l, Wr, Wn, bs, acc); }
    __syncthreads();
    if (n >= 0) {
#pragma unroll
      for (int c = 0; c < 15; c++) h_l[n * HLS + cb + c] = acc[c];
    }
    __syncthreads();
    norm_pool(h_l, pooled_l, l + 1, tid);
    __syncthreads();
  }

  // ---- final MLP ----
  if (tid < 50) {
    float a = fc1b[tid];
    for (int i = 0; i < 10 * CC; i++) a = fmaf(pooled_l[i], fc1w[i * 50 + tid], a);
    fch[tid] = fmaxf(a, 0.f);
  }
  __syncthreads();
  if (tid < 2) {
    float o = fc2b[tid];
#pragma unroll
    for (int j = 0; j < 50; j++) o = fmaf(fch[j], fc2w[j * 2 + tid], o);
    out[g * 2 + tid] = o;
  }
}

extern "C" void kernel_launch(void* const* d_in, const int* in_sizes, int n_in,
                              void* d_out, int out_size, void* d_ws, size_t ws_size,
                              hipStream_t stream) {
  (void)d_ws; (void)ws_size; (void)in_sizes; (void)n_in; (void)out_size;
  const float* x     = (const float*)d_in[0];
  const int*   ei    = (const int*)d_in[1];
  const float* eattr = (const float*)d_in[2];
  const float* egw   = (const float*)d_in[4];
  const float* att_s = (const float*)d_in[5];
  const float* att_d = (const float*)d_in[6];
  const float* att_e = (const float*)d_in[7];
  const float* wroot = (const float*)d_in[8];
  const float* wnbr  = (const float*)d_in[9];
  const float* gcb   = (const float*)d_in[10];
  const float* fc1w  = (const float*)d_in[11];
  const float* fc1b  = (const float*)d_in[12];
  const float* fc2w  = (const float*)d_in[13];
  const float* fc2b  = (const float*)d_in[14];
  float* out = (float*)d_out;

  k_mega<<<GN, 1024, 0, stream>>>(x, ei, eattr, egw, att_s, att_d, att_e,
                                  wroot, wnbr, gcb, fc1w, fc1b, fc2w, fc2b, out);
}

// Round 14
// 219.649 us; speedup vs baseline: 1.2683x; 1.2683x over previous
//
#include <hip/hip_runtime.h>
#include <hip/hip_fp16.h>

#define GN 256
#define NPG 360
#define NN (GN*NPG)      // 92160
#define DEGAVG 16
#define EE (NN*DEGAVG)   // 1474560
#define EPG (NPG*DEGAVG) // 5760 edges per graph
#define HH 5
#define CC 30
#define IN_CH 11
#define NUM_GC 9
#define EPS 1e-5f

#define HLS 35   // h_l f32 row stride: 3 mod 32, coprime -> conflict-free b32 patterns
#define AGS 33   // agg row stride: (n+k)%32 distinct
#define SSS 5    // ssrc/sdst row stride
#define XS 12    // x row stride (floats): 16B-aligned rows

// ---- LDS layout (bytes) ----
#define OFF_HL     0        // float[360*35] = 50400
#define OFF_EDGE   50400    // uint [5760]   = 23040
#define OFF_UNI    73440    // 47520: EGAT {x 17280 | ssrc 7200 | sdst 7200} / GC {agg 47520}
#define OFF_ROWP   120960   // u16  [364]    = 728
#define OFF_DEG    121688   // uint [360]    = 1440
#define OFF_POOL   123128   // float[300]    = 1200
#define OFF_FCH    124328   // float[56]     = 224
#define OFF_WA     124552   // float[112]    = 448
#define OFF_WSUM   125000   // uint [18]     = 72
#define SMEM_TOTAL 125072

__device__ __forceinline__ float f16_to_f32(unsigned short us) {
  __half_raw r; r.x = us; return __half2float(r);
}
__device__ __forceinline__ unsigned short f32_to_f16(float f) {
  __half h = __float2half(f);
  __half_raw r = *reinterpret_cast<__half_raw*>(&h);
  return r.x;
}

// ---------- InstanceNorm (in place, f32) + per-graph max pool: 30 ch x 32 lanes ----------
__device__ __forceinline__ void norm_pool(float* h_l, float* pooled_l, int layer, int tid) {
  int c = tid >> 5, jj = tid & 31;
  if (c < CC) {
    float va[12];
    float s = 0.f, s2 = 0.f;
#pragma unroll
    for (int t = 0; t < 12; t++) {
      int i = jj + t * 32;
      float v = (i < NPG) ? h_l[i * HLS + c] : 0.f;
      va[t] = v; s += v; s2 += v * v;
    }
#pragma unroll
    for (int m = 16; m >= 1; m >>= 1) { s += __shfl_xor(s, m); s2 += __shfl_xor(s2, m); }
    float mean = s * (1.f / NPG);
    float rs = rsqrtf(s2 * (1.f / NPG) - mean * mean + EPS);
    float mx = -1e30f;
#pragma unroll
    for (int t = 0; t < 12; t++) {
      int i = jj + t * 32;
      if (i < NPG) {
        float v = (va[t] - mean) * rs;
        h_l[i * HLS + c] = v;
        mx = fmaxf(mx, v);
      }
    }
#pragma unroll
    for (int m = 16; m >= 1; m >>= 1) mx = fmaxf(mx, __shfl_xor(mx, m));
    if (jj == 0) pooled_l[layer * CC + c] = mx;
  }
}

// ---------- GraphConv matmul half (compile-time channel base -> scalar weight loads) ----------
template <int CB>
__device__ __forceinline__ void mm_half(int n, const float* h_l, const float* agg_l,
                                        const float* Wr, const float* Wn, const float* bs,
                                        float* acc) {
#pragma unroll
  for (int c = 0; c < 15; c++) acc[c] = bs[CB + c];
  const float* hr = h_l + n * HLS;
  const float* ar = agg_l + n * AGS;
#pragma unroll
  for (int k = 0; k < CC; k++) {
    float hk = hr[k];
#pragma unroll
    for (int c = 0; c < 15; c++) acc[c] = fmaf(hk, Wr[k * CC + CB + c], acc[c]);
  }
#pragma unroll
  for (int k = 0; k < CC; k++) {
    float ak = ar[k];
#pragma unroll
    for (int c = 0; c < 15; c++) acc[c] = fmaf(ak, Wn[k * CC + CB + c], acc[c]);
  }
}

// ---------- mega-kernel ----------
__global__ __launch_bounds__(1024, 4) void k_mega(
    const float* __restrict__ x, const int* __restrict__ ei, const float* __restrict__ eattr,
    const float* __restrict__ egw, const float* __restrict__ att_s,
    const float* __restrict__ att_d, const float* __restrict__ att_e,
    const float* __restrict__ wroot, const float* __restrict__ wnbr,
    const float* __restrict__ gcb,
    const float* __restrict__ fc1w, const float* __restrict__ fc1b,
    const float* __restrict__ fc2w, const float* __restrict__ fc2b,
    float* __restrict__ out) {
  __shared__ __align__(16) unsigned char smem[SMEM_TOTAL];
  float*          h_l     = (float*)(smem + OFF_HL);
  unsigned*       edge_l  = (unsigned*)(smem + OFF_EDGE);
  float*          x_l     = (float*)(smem + OFF_UNI);
  float*          ssrc_l  = (float*)(smem + OFF_UNI) + NPG * XS;
  float*          sdst_l  = (float*)(smem + OFF_UNI) + NPG * XS + NPG * SSS;
  float*          agg_l   = (float*)(smem + OFF_UNI);          // GC-phase alias
  unsigned short* rowp_l  = (unsigned short*)(smem + OFF_ROWP);
  unsigned*       deg_l   = (unsigned*)(smem + OFF_DEG);
  float*          pooled_l= (float*)(smem + OFF_POOL);
  float*          fch     = (float*)(smem + OFF_FCH);
  float*          wa_l    = (float*)(smem + OFF_WA);
  unsigned*       wsum    = (unsigned*)(smem + OFF_WSUM);

  const int g = blockIdx.x, tid = threadIdx.x;
  const int nb = g * NPG;
  const int ebase = g * EPG;            // edges are graph-contiguous by construction
  const int lane = tid & 63, wid = tid >> 6;

  // ---- P0: zero deg, stage x (f32, padded rows of 12) ----
  for (int i = tid; i < NPG; i += 1024) deg_l[i] = 0u;
  for (int it = tid; it < NPG * XS; it += 1024) {
    int n = it / XS, i = it - n * XS;
    x_l[it] = (i < IN_CH) ? x[(size_t)(nb + n) * IN_CH + i] : 0.f;
  }
  __syncthreads();

  // ---- P1: degree histogram (LDS atomics) + wa precontraction ----
  for (int e = tid; e < EPG; e += 1024) {
    int d = ei[EE + ebase + e] - nb;
    atomicAdd(&deg_l[d], 1u);
  }
  if (tid < 110) {
    int half = tid >= 55;
    int idx = tid - half * 55;
    int i = idx / 5, h = idx - i * 5;
    const float* av = half ? att_d : att_s;
    float s = 0.f;
#pragma unroll
    for (int c = 0; c < CC; c++) s += egw[(i * HH + h) * CC + c] * av[h * CC + c];
    wa_l[tid] = s;
  }
  __syncthreads();

  // ---- P2: block scan of degrees -> rowp_l ----
  {
    unsigned v = (tid < NPG) ? deg_l[tid] : 0u;
#pragma unroll
    for (int off = 1; off < 64; off <<= 1) {
      unsigned t = (unsigned)__shfl_up((int)v, off);
      if (lane >= off) v += t;
    }
    if (lane == 63) wsum[wid] = v;
    __syncthreads();
    if (tid == 0) {
      unsigned run = 0;
      for (int i = 0; i < 16; i++) { unsigned t = wsum[i]; wsum[i] = run; run += t; }
    }
    __syncthreads();
    if (tid < NPG) rowp_l[tid + 1] = (unsigned short)(v + wsum[wid]);
    if (tid == 0) rowp_l[0] = 0;
    if (tid < NPG) deg_l[tid] = 0u;     // becomes scatter cursor
  }
  __syncthreads();

  // ---- P3: scatter edges into CSR (raw src | eattr_f16) + ssrc/sdst dots ----
  for (int e = tid; e < EPG; e += 1024) {
    int s = ei[ebase + e] - nb;
    int d = ei[EE + ebase + e] - nb;
    float ea = eattr[ebase + e];
    unsigned pos = (unsigned)rowp_l[d] + atomicAdd(&deg_l[d], 1u);
    edge_l[pos] = (unsigned)s | ((unsigned)f32_to_f16(ea) << 16);
  }
  if (tid < NPG) {
    float xi[IN_CH];
#pragma unroll
    for (int i = 0; i < IN_CH; i++) xi[i] = x_l[tid * XS + i];
#pragma unroll
    for (int h = 0; h < HH; h++) {
      float s1 = 0.f, s2 = 0.f;
#pragma unroll
      for (int i = 0; i < IN_CH; i++) {
        s1 = fmaf(xi[i], wa_l[i * HH + h], s1);
        s2 = fmaf(xi[i], wa_l[55 + i * HH + h], s2);
      }
      ssrc_l[tid * SSS + h] = s1;
      sdst_l[tid * SSS + h] = s2;
    }
  }
  __syncthreads();

  // ---- P4: EGAT thread-per-node, 2 passes (max-shift cancels; |logit| small) ----
  if (tid < NPG) {
    const int n = tid;
    const int b = rowp_l[n], en = rowp_l[n + 1];
    float sd[HH], ae[HH];
#pragma unroll
    for (int h = 0; h < HH; h++) { sd[h] = sdst_l[n * SSS + h]; ae[h] = att_e[h]; }
    float dn[HH];
#pragma unroll
    for (int h = 0; h < HH; h++) dn[h] = 0.f;
    // pass 1: denominators, 2-unrolled for load-latency overlap
    int p = b;
    for (; p + 1 < en; p += 2) {
      unsigned ua = edge_l[p], ub = edge_l[p + 1];
      int sa_ = ua & 0xffffu, sb_ = ub & 0xffffu;
      float eaa = f16_to_f32((unsigned short)(ua >> 16));
      float eab = f16_to_f32((unsigned short)(ub >> 16));
      const float* sra = ssrc_l + sa_ * SSS;
      const float* srb = ssrc_l + sb_ * SSS;
#pragma unroll
      for (int h = 0; h < HH; h++) {
        float la = sra[h] + sd[h] + eaa * ae[h];
        float lb = srb[h] + sd[h] + eab * ae[h];
        la = la > 0.f ? la : 0.2f * la;
        lb = lb > 0.f ? lb : 0.2f * lb;
        dn[h] += __expf(la) + __expf(lb);
      }
    }
    if (p < en) {
      unsigned u = edge_l[p];
      int s = u & 0xffffu;
      float ea = f16_to_f32((unsigned short)(u >> 16));
      const float* sr = ssrc_l + s * SSS;
#pragma unroll
      for (int h = 0; h < HH; h++) {
        float lg = sr[h] + sd[h] + ea * ae[h];
        lg = lg > 0.f ? lg : 0.2f * lg;
        dn[h] += __expf(lg);
      }
    }
    float rdn[HH];
#pragma unroll
    for (int h = 0; h < HH; h++) rdn[h] = 1.f / (dn[h] + 1e-16f);
    float gg[55];
#pragma unroll
    for (int k = 0; k < 55; k++) gg[k] = 0.f;
    for (p = b; p < en; p++) {                // pass 2: alpha, 11-dim gather, edge rewrite
      unsigned u = edge_l[p];
      int s = u & 0xffffu;
      float ea = f16_to_f32((unsigned short)(u >> 16));
      const float* sr = ssrc_l + s * SSS;
      const float* xr = x_l + s * XS;
      const float4 xv0 = *(const float4*)(xr);
      const float4 xv1 = *(const float4*)(xr + 4);
      const float4 xv2 = *(const float4*)(xr + 8);
      const float xi[IN_CH] = {xv0.x, xv0.y, xv0.z, xv0.w, xv1.x, xv1.y, xv1.z, xv1.w,
                               xv2.x, xv2.y, xv2.z};
      float ews = 0.f;
#pragma unroll
      for (int h = 0; h < HH; h++) {
        float lg = sr[h] + sd[h] + ea * ae[h];
        lg = lg > 0.f ? lg : 0.2f * lg;
        float a = __expf(lg) * rdn[h];
        ews += a;
#pragma unroll
        for (int i = 0; i < IN_CH; i++) gg[h * IN_CH + i] = fmaf(a, xi[i], gg[h * IN_CH + i]);
      }
      // rewrite edge: premultiplied h_l float offset | f16(mean-head alpha)
      edge_l[p] = (unsigned)(s * HLS) | ((unsigned)f32_to_f16(ews * 0.2f) << 16);
    }
    // h = 0.2 * sum_h g_h . W_h  (uniform scalar weight loads)
#pragma unroll
    for (int half = 0; half < 2; half++) {
      float acc[15];
#pragma unroll
      for (int c = 0; c < 15; c++) acc[c] = 0.f;
#pragma unroll
      for (int i = 0; i < IN_CH; i++) {
#pragma unroll
        for (int h = 0; h < HH; h++) {
          float gv = gg[h * IN_CH + i];
          const float* wr = egw + (i * HH + h) * CC + half * 15;
#pragma unroll
          for (int c = 0; c < 15; c++) acc[c] = fmaf(gv, wr[c], acc[c]);
        }
      }
#pragma unroll
      for (int c = 0; c < 15; c++) h_l[n * HLS + half * 15 + c] = 0.2f * acc[c];
    }
  }
  __syncthreads();

  // ---- P5: norm0 + pooled[0] ----
  norm_pool(h_l, pooled_l, 0, tid);
  __syncthreads();

  // ---- GC stack ----
  const int es = lane >> 5;          // edge slot 0/1
  const int cg = lane & 31;          // channel (30,31 dummy)
#pragma unroll 1
  for (int l = 0; l < NUM_GC; l++) {
    // gather: wave per node, 2 edges x 32 channels; banks (3s+c)%32 -> 2-way (free).
    // 4-deep unroll, 4 independent accumulators: 4 edge loads + 4 h loads issue
    // back-to-back -> load latency amortized 4x (R7 was a serial 1-deep chain).
    for (int n = wid; n < NPG; n += 16) {
      int b = rowp_l[n], en = rowp_l[n + 1];
      float a0 = 0.f, a1 = 0.f, a2 = 0.f, a3 = 0.f;
      int p = b + es;
      for (; p + 6 < en; p += 8) {
        unsigned u0 = edge_l[p];
        unsigned u1 = edge_l[p + 2];
        unsigned u2 = edge_l[p + 4];
        unsigned u3 = edge_l[p + 6];
        float h0 = h_l[(u0 & 0xffffu) + cg];
        float h1 = h_l[(u1 & 0xffffu) + cg];
        float h2 = h_l[(u2 & 0xffffu) + cg];
        float h3 = h_l[(u3 & 0xffffu) + cg];
        a0 = fmaf(f16_to_f32((unsigned short)(u0 >> 16)), h0, a0);
        a1 = fmaf(f16_to_f32((unsigned short)(u1 >> 16)), h1, a1);
        a2 = fmaf(f16_to_f32((unsigned short)(u2 >> 16)), h2, a2);
        a3 = fmaf(f16_to_f32((unsigned short)(u3 >> 16)), h3, a3);
      }
      for (; p < en; p += 2) {
        unsigned u = edge_l[p];
        a0 = fmaf(f16_to_f32((unsigned short)(u >> 16)), h_l[(u & 0xffffu) + cg], a0);
      }
      float a = (a0 + a1) + (a2 + a3);
      a += __shfl_xor(a, 32);
      if (lane < CC) agg_l[n * AGS + lane] = a;
    }
    __syncthreads();
    // matmul halves: compute (reads) -> barrier -> write (avoids cross-half RW race)
    const float* Wr = wroot + l * CC * CC;
    const float* Wn = wnbr + l * CC * CC;
    const float* bs = gcb + l * CC;
    float acc[15];
    int n = -1, cb = 0;
    if (tid < NPG) { n = tid; cb = 0; mm_half<0>(n, h_l, agg_l, Wr, Wn, bs, acc); }
    else if (tid >= 512 && tid < 512 + NPG) { n = tid - 512; cb = 15; mm_half<15>(n, h_l, agg_l, Wr, Wn, bs, acc); }
    __syncthreads();
    if (n >= 0) {
#pragma unroll
      for (int c = 0; c < 15; c++) h_l[n * HLS + cb + c] = acc[c];
    }
    __syncthreads();
    norm_pool(h_l, pooled_l, l + 1, tid);
    __syncthreads();
  }

  // ---- final MLP ----
  if (tid < 50) {
    float a = fc1b[tid];
    for (int i = 0; i < 10 * CC; i++) a = fmaf(pooled_l[i], fc1w[i * 50 + tid], a);
    fch[tid] = fmaxf(a, 0.f);
  }
  __syncthreads();
  if (tid < 2) {
    float o = fc2b[tid];
#pragma unroll
    for (int j = 0; j < 50; j++) o = fmaf(fch[j], fc2w[j * 2 + tid], o);
    out[g * 2 + tid] = o;
  }
}

extern "C" void kernel_launch(void* const* d_in, const int* in_sizes, int n_in,
                              void* d_out, int out_size, void* d_ws, size_t ws_size,
                              hipStream_t stream) {
  (void)d_ws; (void)ws_size; (void)in_sizes; (void)n_in; (void)out_size;
  const float* x     = (const float*)d_in[0];
  const int*   ei    = (const int*)d_in[1];
  const float* eattr = (const float*)d_in[2];
  const float* egw   = (const float*)d_in[4];
  const float* att_s = (const float*)d_in[5];
  const float* att_d = (const float*)d_in[6];
  const float* att_e = (const float*)d_in[7];
  const float* wroot = (const float*)d_in[8];
  const float* wnbr  = (const float*)d_in[9];
  const float* gcb   = (const float*)d_in[10];
  const float* fc1w  = (const float*)d_in[11];
  const float* fc1b  = (const float*)d_in[12];
  const float* fc2w  = (const float*)d_in[13];
  const float* fc2b  = (const float*)d_in[14];
  float* out = (float*)d_out;

  k_mega<<<GN, 1024, 0, stream>>>(x, ei, eattr, egw, att_s, att_d, att_e,
                                  wroot, wnbr, gcb, fc1w, fc1b, fc2w, fc2b, out);
}